// Round 9
// baseline (183227.124 us; speedup 1.0000x reference)
//
#include <hip/hip_runtime.h>
#include <hip/hip_bf16.h>

// B=32, T=2048, I=H=512, L=4. Output = stacked final cell states c_n (L,B,H).
// Fused persistent kernel, 256 WGs. Domains (layer,bg)=32 WGs claimed onto one
// XCD via a lock-free pool claim (no global barrier). Within-layer recurrence
// syncs through the XCD-local L2 (plain write-through stores + sc0-only tagged
// polls, bounded retries); cross-layer and all fallbacks use the proven
// device-scope tagged polling (R5). Producers always dual-store, so the
// device-scope path guarantees liveness regardless of XCD placement.
#define BATCH   32
#define SEQT    2048
#define HDIM    512
#define LAYERS  4
#define RINGW   8
#define CHK     4
#define NTHR    256
#define NWG     256
#define CPAD    32       // ints per counter slot (128 B line)

typedef short short8 __attribute__((ext_vector_type(8)));
typedef float f32x4  __attribute__((ext_vector_type(4)));
typedef unsigned int uint4v __attribute__((ext_vector_type(4)));
typedef unsigned short ushort;
typedef unsigned int uint;

__device__ __forceinline__ float bf2f(ushort u) {
    return __uint_as_float(((uint)u) << 16);
}
__device__ __forceinline__ ushort f2bf(float f) {
    uint u = __float_as_uint(f);
    u = (u + 0x7FFF + ((u >> 16) & 1)) >> 16;   // RNE
    return (ushort)u;
}
__device__ __forceinline__ float sigmoid_fast(float x) {
    return 1.0f / (1.0f + __expf(-x));
}
__device__ __forceinline__ float tanh_fast(float x) {
    return 1.0f - 2.0f / (__expf(2.0f * x) + 1.0f);
}

// ---- coherent probes ----
__device__ __forceinline__ uint probe_dev(const uint* p) {   // IF-coherent
    uint r;
    asm volatile("global_load_dword %0, %1, off sc0 sc1\n\ts_waitcnt vmcnt(0)"
                 : "=v"(r) : "v"(p) : "memory");
    return r;
}
__device__ __forceinline__ uint probe_l2(const uint* p) {    // XCD-L2 read
    uint r;
    asm volatile("global_load_dword %0, %1, off sc0\n\ts_waitcnt vmcnt(0)"
                 : "=v"(r) : "v"(p) : "memory");
    return r;
}

// ---- bulk fragment loads: 16x dwordx4 in flight, one latency (waited) ----
#define BULK_BODY(FLAGS)                                                      \
    asm volatile(                                                             \
        "global_load_dwordx4 %0, %16, off " FLAGS "\n\t"                      \
        "global_load_dwordx4 %1, %16, off offset:16 " FLAGS "\n\t"            \
        "global_load_dwordx4 %2, %16, off offset:128 " FLAGS "\n\t"           \
        "global_load_dwordx4 %3, %16, off offset:144 " FLAGS "\n\t"           \
        "global_load_dwordx4 %4, %16, off offset:256 " FLAGS "\n\t"           \
        "global_load_dwordx4 %5, %16, off offset:272 " FLAGS "\n\t"           \
        "global_load_dwordx4 %6, %16, off offset:384 " FLAGS "\n\t"           \
        "global_load_dwordx4 %7, %16, off offset:400 " FLAGS "\n\t"           \
        "global_load_dwordx4 %8, %16, off offset:512 " FLAGS "\n\t"           \
        "global_load_dwordx4 %9, %16, off offset:528 " FLAGS "\n\t"           \
        "global_load_dwordx4 %10, %16, off offset:640 " FLAGS "\n\t"          \
        "global_load_dwordx4 %11, %16, off offset:656 " FLAGS "\n\t"          \
        "global_load_dwordx4 %12, %16, off offset:768 " FLAGS "\n\t"          \
        "global_load_dwordx4 %13, %16, off offset:784 " FLAGS "\n\t"          \
        "global_load_dwordx4 %14, %16, off offset:896 " FLAGS "\n\t"          \
        "global_load_dwordx4 %15, %16, off offset:912 " FLAGS "\n\t"          \
        "s_waitcnt vmcnt(0)"                                                  \
        : "=&v"(a0), "=&v"(a1), "=&v"(a2), "=&v"(a3),                         \
          "=&v"(a4), "=&v"(a5), "=&v"(a6), "=&v"(a7),                         \
          "=&v"(a8), "=&v"(a9), "=&v"(a10), "=&v"(a11),                       \
          "=&v"(a12), "=&v"(a13), "=&v"(a14), "=&v"(a15)                      \
        : "v"(p) : "memory")

__device__ __forceinline__ void bulk16_dev(const uint* p,
    uint4v& a0, uint4v& a1, uint4v& a2,  uint4v& a3,
    uint4v& a4, uint4v& a5, uint4v& a6,  uint4v& a7,
    uint4v& a8, uint4v& a9, uint4v& a10, uint4v& a11,
    uint4v& a12, uint4v& a13, uint4v& a14, uint4v& a15) {
    BULK_BODY("sc0 sc1");
}
__device__ __forceinline__ void bulk16_l2(const uint* p,
    uint4v& a0, uint4v& a1, uint4v& a2,  uint4v& a3,
    uint4v& a4, uint4v& a5, uint4v& a6,  uint4v& a7,
    uint4v& a8, uint4v& a9, uint4v& a10, uint4v& a11,
    uint4v& a12, uint4v& a13, uint4v& a14, uint4v& a15) {
    BULK_BODY("sc0");
}

template <typename T> struct IO;
template <> struct IO<ushort> {
    static constexpr int IS_F32 = 0;
    static __device__ __forceinline__ float  ld (const ushort* p) { return bf2f(*p); }
    static __device__ __forceinline__ short8 ld8(const ushort* p) { return *(const short8*)p; }
    static __device__ __forceinline__ void   st (ushort* p, float v) { *p = f2bf(v); }
};
template <> struct IO<float> {
    static constexpr int IS_F32 = 1;
    static __device__ __forceinline__ float  ld (const float* p) { return *p; }
    static __device__ __forceinline__ short8 ld8(const float* p) {
        short8 r;
        #pragma unroll
        for (int i = 0; i < 8; ++i) r[i] = (short)f2bf(p[i]);
        return r;
    }
    static __device__ __forceinline__ void   st (float* p, float v) { *p = v; }
};

__global__ void zero_ints_kernel(int* p) { p[blockIdx.x * 1024 + threadIdx.x] = 0; }
__global__ void zero_ring_kernel(uint4v* r) {
    r[blockIdx.x * 256 + threadIdx.x] = (uint4v){0, 0, 0, 0};
}
__global__ void detect_kernel(const ushort* x, int* flag) {
    int bad = 0;
    for (int i = threadIdx.x; i < 4096; i += 256)
        if (((x[i] >> 7) & 0xFF) >= 0xC0) bad = 1;
    if (bad)
        __hip_atomic_fetch_or(flag, 1, __ATOMIC_RELEASE, __HIP_MEMORY_SCOPE_AGENT);
}
__device__ __forceinline__ void spin_ge(int* p, int target) {
    while (__hip_atomic_load(p, __ATOMIC_RELAXED, __HIP_MEMORY_SCOPE_AGENT) < target)
        __builtin_amdgcn_s_sleep(1);
}

// validate-and-repack macro bodies (R6-proven pattern, named vars)
#define TAGS_BAD(WV)                                                          \
    ( (((w0 >> 16) ^ WV) | ((w1 >> 16) ^ WV) | ((w2 >> 16) ^ WV)              \
     | ((w3 >> 16) ^ WV) | ((w4 >> 16) ^ WV) | ((w5 >> 16) ^ WV)              \
     | ((w6 >> 16) ^ WV) | ((w7 >> 16) ^ WV) | ((w8 >> 16) ^ WV)              \
     | ((w9 >> 16) ^ WV) | ((w10 >> 16) ^ WV) | ((w11 >> 16) ^ WV)            \
     | ((w12 >> 16) ^ WV) | ((w13 >> 16) ^ WV) | ((w14 >> 16) ^ WV)           \
     | ((w15 >> 16) ^ WV)) )
#define RPK(IT, WA, WB) { short8 v_;                                          \
    v_[0]=(short)WA[0]; v_[1]=(short)WA[1];                                   \
    v_[2]=(short)WA[2]; v_[3]=(short)WA[3];                                   \
    v_[4]=(short)WB[0]; v_[5]=(short)WB[1];                                   \
    v_[6]=(short)WB[2]; v_[7]=(short)WB[3]; av[IT]=v_; }
#define RPK_ALL()                                                             \
    RPK(0, w0,  w1)  RPK(1, w2,  w3)  RPK(2, w4,  w5)  RPK(3, w6,  w7)        \
    RPK(4, w8,  w9)  RPK(5, w10, w11) RPK(6, w12, w13) RPK(7, w14, w15)

template <typename T>
__global__ __launch_bounds__(NTHR, 1) void lstm_fused_kernel(
    const T* __restrict__ x, const T* __restrict__ h0, const T* __restrict__ c0,
    const T* __restrict__ wih, const T* __restrict__ whh,
    const T* __restrict__ bih, const T* __restrict__ bhh,
    T* __restrict__ c_out,
    uint* gring,   // [L][RINGW][BATCH][HDIM] tagged words, device-scope (2 MiB)
    uint* lring,   // [8 domains][RINGW][16][HDIM] tagged words, XCD-local (2 MiB)
    int*  cnt)
{
    {   // dtype gate (before any claiming)
        int fl = __hip_atomic_load(&cnt[512], __ATOMIC_ACQUIRE, __HIP_MEMORY_SCOPE_AGENT);
        if ((fl != 0) != (IO<T>::IS_F32 != 0)) return;
    }
    const int tid = threadIdx.x;

    // ---- lock-free XCD pool claim: domain d = XCD d (32 slots each) ----
    __shared__ int rsh[3];
    if (tid == 0) {
        uint xcc;
        asm volatile("s_getreg_b32 %0, hwreg(HW_REG_XCC_ID)" : "=s"(xcc));
        xcc &= 7u;
        int* pools  = cnt + 32 * CPAD;   // 8 pools
        int* dmatch = cnt + 48 * CPAD;   // 8 match counters
        int* darr   = cnt + 56 * CPAD;   // 8 arrival counters
        int dom = -1, slot = -1;
        int s = __hip_atomic_fetch_add(&pools[xcc * CPAD], 1, __ATOMIC_RELAXED, __HIP_MEMORY_SCOPE_AGENT);
        if (s < 32) { dom = (int)xcc; slot = s; }
        else {
            int p = (int)xcc;
            for (;;) {
                p = (p + 1) & 7;
                int c = __hip_atomic_load(&pools[p * CPAD], __ATOMIC_RELAXED, __HIP_MEMORY_SCOPE_AGENT);
                if (c < 32) {
                    int s2 = __hip_atomic_fetch_add(&pools[p * CPAD], 1, __ATOMIC_RELAXED, __HIP_MEMORY_SCOPE_AGENT);
                    if (s2 < 32) { dom = p; slot = s2; break; }
                }
                if (p == (int)xcc) __builtin_amdgcn_s_sleep(1);
            }
        }
        if (dom == (int)xcc)
            __hip_atomic_fetch_add(&dmatch[dom * CPAD], 1, __ATOMIC_RELAXED, __HIP_MEMORY_SCOPE_AGENT);
        __hip_atomic_fetch_add(&darr[dom * CPAD], 1, __ATOMIC_RELEASE, __HIP_MEMORY_SCOPE_AGENT);
        while (__hip_atomic_load(&darr[dom * CPAD], __ATOMIC_ACQUIRE, __HIP_MEMORY_SCOPE_AGENT) < 32)
            __builtin_amdgcn_s_sleep(1);
        int m = __hip_atomic_load(&dmatch[dom * CPAD], __ATOMIC_RELAXED, __HIP_MEMORY_SCOPE_AGENT);
        rsh[0] = dom; rsh[1] = slot; rsh[2] = (m == 32);
    }
    __syncthreads();
    const int  dom  = rsh[0];
    const int  l    = dom >> 1;          // layer 0..3
    const int  bg   = dom & 1;           // batch group
    const int  ug   = rsh[1];            // unit group 0..31
    const bool unif = rsh[2] != 0;

    const int wave  = tid >> 6;
    const int lane  = tid & 63;
    const int lquad = lane >> 4;
    const int l15   = lane & 15;

    __shared__ float pg[2][4][64][20];

    // ---- resident B fragments ----
    short8 bf[4][8];
    {
        const T* wsrc = (wave < 2) ? (wih + (size_t)l * 4 * HDIM * HDIM)
                                   : (whh + (size_t)l * 4 * HDIM * HDIM);
        const int kbase = (wave & 1) * 256;
        const int unit  = ug * 16 + l15;
        #pragma unroll
        for (int sub = 0; sub < 4; ++sub) {
            const T* rp = wsrc + (size_t)(sub * HDIM + unit) * HDIM + kbase + lquad * 8;
            #pragma unroll
            for (int it = 0; it < 8; ++it)
                bf[sub][it] = IO<T>::ld8(rp + it * 32);
        }
    }

    // ---- per-thread recurrent state ----
    const int eb = tid >> 4;
    const int eu = tid & 15;
    const int gb = bg * 16 + eb;
    const int gu = ug * 16 + eu;
    float c_state = IO<T>::ld(c0 + (size_t)l * BATCH * HDIM + gb * HDIM + gu);
    float bias[4];
    #pragma unroll
    for (int g = 0; g < 4; ++g)
        bias[g] = IO<T>::ld(bih + l * 4 * HDIM + g * HDIM + gu) +
                  IO<T>::ld(bhh + l * 4 * HDIM + g * HDIM + gu);

    const int ab = bg * 16 + l15;
    uint* lring_d = lring + (size_t)dom * (RINGW * 16 * HDIM);
    int* c_own  = cnt + dom * CPAD;
    int* c_cons = (l < LAYERS - 1) ? (cnt + (dom + 2) * CPAD) : nullptr;

    for (int t = 0; t < SEQT; ++t) {
        // ---- rare backpressure guard (ring overwrite safety) ----
        if (tid == 0 && (t & (CHK - 1)) == 0 && t >= CHK) {
            int tg = 32 * (t - 3);
            if (tg > 0) spin_ge(c_own, tg);
            if (c_cons) { int tg2 = 32 * (t - 4); if (tg2 > 0) spin_ge(c_cons, tg2); }
        }

        // ---- acquire A fragments ----
        short8 av[8];
        if (wave < 2) {
            if (l == 0) {
                const T* aT = x + ((size_t)ab * SEQT + t) * HDIM + wave * 256 + lquad * 8;
                #pragma unroll
                for (int it = 0; it < 8; ++it) av[it] = IO<T>::ld8(aT + it * 32);
            } else {
                const uint want = (uint)(t + 1);
                const uint* aP = gring + (((size_t)(l - 1) * RINGW + (t & (RINGW - 1))) * BATCH + ab) * HDIM
                                 + wave * 256 + lquad * 8;
                while (!__all((probe_dev(aP + 228) >> 16) == want))
                    __builtin_amdgcn_s_sleep(1);
                uint4v w0,w1,w2,w3,w4,w5,w6,w7,w8,w9,w10,w11,w12,w13,w14,w15;
                uint4v wv = (uint4v){want, want, want, want};
                for (;;) {
                    bulk16_dev(aP, w0,w1,w2,w3,w4,w5,w6,w7,w8,w9,w10,w11,w12,w13,w14,w15);
                    uint4v b4 = TAGS_BAD(wv);
                    if (__all((b4[0] | b4[1] | b4[2] | b4[3]) == 0)) break;
                    __builtin_amdgcn_s_sleep(1);
                }
                RPK_ALL()
            }
        } else {
            if (t == 0) {
                const T* aT = h0 + (size_t)l * BATCH * HDIM + (size_t)ab * HDIM
                              + (wave - 2) * 256 + lquad * 8;
                #pragma unroll
                for (int it = 0; it < 8; ++it) av[it] = IO<T>::ld8(aT + it * 32);
            } else {
                const uint want = (uint)t;
                const uint* aL = lring_d + (((t - 1) & (RINGW - 1)) * 16 + l15) * HDIM
                                 + (wave - 2) * 256 + lquad * 8;
                const uint* aG = gring + (((size_t)l * RINGW + ((t - 1) & (RINGW - 1))) * BATCH + ab) * HDIM
                                 + (wave - 2) * 256 + lquad * 8;
                uint4v w0,w1,w2,w3,w4,w5,w6,w7,w8,w9,w10,w11,w12,w13,w14,w15;
                uint4v wv = (uint4v){want, want, want, want};
                bool got = false;
                if (unif) {
                    // local L2 poll: bounded, falls back to device path
                    int pi = 0;
                    bool fresh = true;
                    while (!__all((probe_l2(aL + 228) >> 16) == want)) {
                        if (++pi > 1024) { fresh = false; break; }
                    }
                    if (fresh) {
                        for (int r = 0; r < 64; ++r) {
                            bulk16_l2(aL, w0,w1,w2,w3,w4,w5,w6,w7,w8,w9,w10,w11,w12,w13,w14,w15);
                            uint4v b4 = TAGS_BAD(wv);
                            if (__all((b4[0] | b4[1] | b4[2] | b4[3]) == 0)) { got = true; break; }
                        }
                    }
                }
                if (!got) {
                    while (!__all((probe_dev(aG + 228) >> 16) == want))
                        __builtin_amdgcn_s_sleep(1);
                    for (;;) {
                        bulk16_dev(aG, w0,w1,w2,w3,w4,w5,w6,w7,w8,w9,w10,w11,w12,w13,w14,w15);
                        uint4v b4 = TAGS_BAD(wv);
                        if (__all((b4[0] | b4[1] | b4[2] | b4[3]) == 0)) break;
                        __builtin_amdgcn_s_sleep(1);
                    }
                }
                RPK_ALL()
            }
        }

        f32x4 acc[4];
        #pragma unroll
        for (int sub = 0; sub < 4; ++sub) acc[sub] = (f32x4){0.f, 0.f, 0.f, 0.f};
        #pragma unroll
        for (int it = 0; it < 8; ++it) {
            #pragma unroll
            for (int sub = 0; sub < 4; ++sub)
                acc[sub] = __builtin_amdgcn_mfma_f32_16x16x32_bf16(av[it], bf[sub][it], acc[sub], 0, 0, 0);
        }

        // D layout (m89): col = lane&15, row = quad*4 + reg
        float (*pgb)[64][20] = pg[t & 1];
        #pragma unroll
        for (int sub = 0; sub < 4; ++sub)
            *(f32x4*)&pgb[wave][sub * 16 + l15][lquad * 4] = acc[sub];
        __syncthreads();   // the one barrier per step

        // ---- epilogue ----
        float gs[4];
        #pragma unroll
        for (int g = 0; g < 4; ++g) {
            float s = bias[g];
            #pragma unroll
            for (int w2 = 0; w2 < 4; ++w2) s += pgb[w2][g * 16 + eu][eb];
            gs[g] = s;
        }
        float ig = sigmoid_fast(gs[0]);
        float fg = sigmoid_fast(gs[1]);
        float gg = tanh_fast(gs[2]);
        float og = sigmoid_fast(gs[3]);
        c_state = fg * c_state + ig * gg;
        float hv = og * tanh_fast(c_state);

        const uint val = ((uint)(t + 1) << 16) | (uint)f2bf(hv);
        // peers (same XCD): plain write-through store -> local L2
        __hip_atomic_store(lring_d + ((t & (RINGW - 1)) * 16 + eb) * HDIM + gu, val,
                           __ATOMIC_RELAXED, __HIP_MEMORY_SCOPE_WORKGROUP);
        // next layer + liveness fallback: device-scope write-through (always)
        __hip_atomic_store(gring + (((size_t)l * RINGW + (t & (RINGW - 1))) * BATCH + gb) * HDIM + gu, val,
                           __ATOMIC_RELAXED, __HIP_MEMORY_SCOPE_AGENT);
        if (t == SEQT - 1)
            IO<T>::st(c_out + (size_t)l * BATCH * HDIM + gb * HDIM + gu, c_state);

        if (tid == 0)   // backpressure count only (slack >= 3 steps)
            __hip_atomic_fetch_add(c_own, 1, __ATOMIC_RELAXED, __HIP_MEMORY_SCOPE_AGENT);
    }
}

extern "C" void kernel_launch(void* const* d_in, const int* in_sizes, int n_in,
                              void* d_out, int out_size, void* d_ws, size_t ws_size,
                              hipStream_t stream) {
    (void)in_sizes; (void)n_in; (void)out_size; (void)ws_size;

    // ws: [0, 8K) counters/pools/dtype flag; [8K, 8K+2M) gring; [+2M, +4M) lring
    int*  cnt   = (int*)d_ws;
    uint* gring = (uint*)((char*)d_ws + 8192);
    uint* lring = (uint*)((char*)d_ws + 8192 + 2097152);

    zero_ints_kernel<<<2, 1024, 0, stream>>>(cnt);
    zero_ring_kernel<<<1024, 256, 0, stream>>>((uint4v*)gring);   // 4 MiB
    detect_kernel<<<1, 256, 0, stream>>>((const ushort*)d_in[0], &cnt[512]);

    lstm_fused_kernel<ushort><<<NWG, NTHR, 0, stream>>>(
        (const ushort*)d_in[0], (const ushort*)d_in[1], (const ushort*)d_in[2],
        (const ushort*)d_in[3], (const ushort*)d_in[4], (const ushort*)d_in[5],
        (const ushort*)d_in[6], (ushort*)d_out, gring, lring, cnt);

    lstm_fused_kernel<float><<<NWG, NTHR, 0, stream>>>(
        (const float*)d_in[0], (const float*)d_in[1], (const float*)d_in[2],
        (const float*)d_in[3], (const float*)d_in[4], (const float*)d_in[5],
        (const float*)d_in[6], (float*)d_out, gring, lring, cnt);
}